// Round 5
// baseline (650.099 us; speedup 1.0000x reference)
//
#include <hip/hip_runtime.h>

// StrokeField R5: spatial counting-sort + per-cell stroke culling.
// R4 post-mortem: direct kernel is at ~57 cyc/wave-point-iter vs ~34 VALU
// floor -> structural ceiling ~300us. But ~92% of the 1.05G point-stroke
// pairs have t==0 exactly (dist > r+0.1 -> clip -> t=0). Exact-skip scheme:
//   K1: contract points, write c to out, cell id (16^3 over [-1,1]^3),
//       histogram via atomics.
//   K2: single-block scan -> 64-aligned cell regions, chunk map, cursors.
//   K3: scatter (cx,cy,cz,idx) into sorted cell regions.
//   K4: per cell, ordered list of strokes reaching the cell AABB
//       (margin 1e-3 >> fp error -> excluded strokes have t==0 EXACTLY).
//   K5: one wave per 64-slot chunk; blend cell's stroke sublist
//       back-to-front (transmittance form, identical math to R2..R4).
// Fallback to the R4 direct kernel if ws_size is too small.

#define NC_DIM 16
#define NC (NC_DIM * NC_DIM * NC_DIM)   // 4096 cells
#define MAXS 512
#define CELL_H  0.125f
#define CELL_INV 8.0f

typedef unsigned short u16;
typedef unsigned long long u64;

__device__ __forceinline__ int cell_of(float cx, float cy, float cz) {
    int ix = (int)floorf((cx + 1.0f) * CELL_INV);
    int iy = (int)floorf((cy + 1.0f) * CELL_INV);
    int iz = (int)floorf((cz + 1.0f) * CELL_INV);
    ix = min(max(ix, 0), NC_DIM - 1);
    iy = min(max(iy, 0), NC_DIM - 1);
    iz = min(max(iz, 0), NC_DIM - 1);
    return ix + NC_DIM * (iy + NC_DIM * iz);
}

// K1: contract, write c to out, cell id + histogram.
__global__ __launch_bounds__(256) void k1_points(
    const float* __restrict__ coords, float* __restrict__ out,
    int* __restrict__ cid, int* __restrict__ cnt, int n)
{
    int i = blockIdx.x * blockDim.x + threadIdx.x;
    if (i >= n) return;
    float x = coords[3 * i], y = coords[3 * i + 1], z = coords[3 * i + 2];
    float n2 = fmaf(x, x, fmaf(y, y, z * z));
    float nn = fmaxf(__builtin_amdgcn_sqrtf(n2), 1e-9f);
    float invn = 1.0f / nn;
    float scl = (nn <= 1.0f) ? 0.5f : (2.0f - invn) * (0.5f * invn);
    float cx = x * scl, cy = y * scl, cz = z * scl;
    float* cw = out + 4 * (size_t)n;
    cw[3 * i] = cx; cw[3 * i + 1] = cy; cw[3 * i + 2] = cz;
    int c = cell_of(cx, cy, cz);
    cid[i] = c;
    atomicAdd(&cnt[c], 1);
}

// K2: single block (1024 thr), scan chunks over 4096 cells.
// cursor[c] = cell slot start (64-aligned); chunkInfo[k] = (cell, slotBase).
__global__ __launch_bounds__(1024) void k2_scan(
    const int* __restrict__ cnt, int* __restrict__ cursor,
    int2* __restrict__ chunkInfo)
{
    __shared__ int waveSums[16];
    int t = threadIdx.x;                 // 0..1023, 4 cells each
    int4 c4 = ((const int4*)cnt)[t];
    int ch[4];
    ch[0] = (c4.x + 63) >> 6; ch[1] = (c4.y + 63) >> 6;
    ch[2] = (c4.z + 63) >> 6; ch[3] = (c4.w + 63) >> 6;
    int s = ch[0] + ch[1] + ch[2] + ch[3];
    int lane = t & 63, wid = t >> 6;
    int v = s;
    for (int off = 1; off < 64; off <<= 1) {
        int u = __shfl_up(v, off, 64);
        if (lane >= off) v += u;
    }
    if (lane == 63) waveSums[wid] = v;
    __syncthreads();
    if (wid == 0) {
        int wv = (lane < 16) ? waveSums[lane] : 0;
        for (int off = 1; off < 16; off <<= 1) {
            int u = __shfl_up(wv, off, 64);
            if (lane >= off) wv += u;
        }
        if (lane < 16) waveSums[lane] = wv;   // inclusive
    }
    __syncthreads();
    int waveOff = (wid == 0) ? 0 : waveSums[wid - 1];
    int running = waveOff + v - s;            // exclusive chunk offset
    for (int k = 0; k < 4; ++k) {
        int c = t * 4 + k;
        cursor[c] = running << 6;             // slot start
        for (int j = 0; j < ch[k]; ++j)
            chunkInfo[running + j] = make_int2(c, (running + j) << 6);
        running += ch[k];
    }
}

// K3: scatter points into sorted cell regions.
__global__ __launch_bounds__(256) void k3_scatter(
    const float* __restrict__ out, const int* __restrict__ cid,
    int* __restrict__ cursor, float4* __restrict__ sorted, int n)
{
    int i = blockIdx.x * blockDim.x + threadIdx.x;
    if (i >= n) return;
    const float* cw = out + 4 * (size_t)n;
    float cx = cw[3 * i], cy = cw[3 * i + 1], cz = cw[3 * i + 2];
    int c = cid[i];
    int pos = atomicAdd(&cursor[c], 1);
    sorted[pos] = make_float4(cx, cy, cz, __int_as_float(i));
}

// K4: one wave per cell -> ordered stroke sublist (AABB-to-sphere test).
__global__ __launch_bounds__(256) void k4_bin(
    const float* __restrict__ shape, u16* __restrict__ cellList,
    int* __restrict__ cellCnt, int ns)
{
    int wave = (blockIdx.x * blockDim.x + threadIdx.x) >> 6;
    int lane = threadIdx.x & 63;
    if (wave >= NC) return;
    int ix = wave & (NC_DIM - 1);
    int iy = (wave >> 4) & (NC_DIM - 1);
    int iz = wave >> 8;
    float lox = -1.0f + ix * CELL_H, hix = lox + CELL_H;
    float loy = -1.0f + iy * CELL_H, hiy = loy + CELL_H;
    float loz = -1.0f + iz * CELL_H, hiz = loz + CELL_H;
    int cnt = 0;
    u16* lst = cellList + (size_t)wave * MAXS;
    for (int base = 0; base < ns; base += 64) {
        int s = base + lane;
        bool pass = false;
        if (s < ns) {
            float4 sp = ((const float4*)shape)[s];
            float dx = sp.x - fminf(fmaxf(sp.x, lox), hix);
            float dy = sp.y - fminf(fmaxf(sp.y, loy), hiy);
            float dz = sp.z - fminf(fmaxf(sp.z, loz), hiz);
            float d2 = fmaf(dx, dx, fmaf(dy, dy, dz * dz));
            float rr = sp.w + 0.101f;          // r + 0.1 + 1e-3 margin
            pass = d2 <= rr * rr;
        }
        u64 m = __ballot(pass);
        if (pass) {
            int p = cnt + __popcll(m & ((1ull << lane) - 1ull));
            lst[p] = (u16)s;
        }
        cnt += __popcll(m);
    }
    if (lane == 0) cellCnt[wave] = cnt;
}

// K5: one wave per 64-slot chunk; blend the cell's stroke sublist.
__global__ __launch_bounds__(256) void k5_blend(
    const float* __restrict__ shape, const float* __restrict__ color,
    const float* __restrict__ alpha,
    const int2* __restrict__ chunkInfo, const float4* __restrict__ sorted,
    const u16* __restrict__ cellList, const int* __restrict__ cellCnt,
    float* __restrict__ out, int n, int ns)
{
    // chunks fill densely from 0 -> if first wave's chunk is sentinel, all are.
    if (chunkInfo[blockIdx.x * 4].x < 0) return;

    __shared__ float4 sA[MAXS];   // (ax, ay, az, K = 0.5 - 5r)
    __shared__ float4 sB[MAXS];   // (dp, cr, cg, cb)
    for (int s = threadIdx.x; s < ns; s += blockDim.x) {
        float4 sp = ((const float4*)shape)[s];
        sA[s] = make_float4(sp.x, sp.y, sp.z, fmaf(-5.0f, sp.w, 0.5f));
        sB[s] = make_float4(fmaxf(alpha[s], 0.0f) * 50.0f,
                            color[3 * s], color[3 * s + 1], color[3 * s + 2]);
    }
    __syncthreads();

    int k = blockIdx.x * 4 + (threadIdx.x >> 6);
    int lane = threadIdx.x & 63;
    int2 info = chunkInfo[k];
    int cell = info.x;
    if (cell < 0) return;

    float4 rec = sorted[info.y + lane];     // pads: NaN coords, idx = -1
    float cx = rec.x, cy = rec.y, cz = rec.z;
    int nl = cellCnt[cell];
    const u16* lst = cellList + (size_t)cell * MAXS;

    float T = 1.0f, Ad = 0.0f, Ar = 0.0f, Ag = 0.0f, Ab = 0.0f;
    for (int jb = (((nl + 63) >> 6) << 6) - 64; jb >= 0; jb -= 64) {
        int jl = jb + lane;
        int myId = (jl < nl) ? (int)lst[jl] : 0;
        int hi = nl - jb; hi = hi > 64 ? 64 : hi;
        int sid = __builtin_amdgcn_readlane(myId, hi - 1);
        float4 a = sA[sid];
        float4 b = sB[sid];
        for (int jj = hi - 1; jj >= 0; --jj) {
            int sidn = __builtin_amdgcn_readlane(myId, jj > 0 ? jj - 1 : 0);
            float4 an = sA[sidn];
            float4 bn = sB[sidn];
            float dx = cx - a.x, dy = cy - a.y, dz = cz - a.z;
            float d2 = fmaf(dx, dx, fmaf(dy, dy, dz * dz));
            float dist = __builtin_amdgcn_sqrtf(d2);
            float omt = fminf(fmaxf(fmaf(5.0f, dist, a.w), 0.0f), 1.0f);
            float Tn = omt * T;
            float tT = T - Tn;
            Ad = fmaf(tT, b.x, Ad);
            Ar = fmaf(tT, b.y, Ar);
            Ag = fmaf(tT, b.z, Ag);
            Ab = fmaf(tT, b.w, Ab);
            T = Tn;
            a = an; b = bn;
        }
    }

    int oi = __float_as_int(rec.w);
    if (oi >= 0) {
        float inv = 1.0f / (1.0f + 1e-6f - T);
        out[oi] = Ad;
        float* rgb = out + n;
        rgb[3 * oi]     = fminf(fmaxf(Ar * inv, 0.0f), 1.0f);
        rgb[3 * oi + 1] = fminf(fmaxf(Ag * inv, 0.0f), 1.0f);
        rgb[3 * oi + 2] = fminf(fmaxf(Ab * inv, 0.0f), 1.0f);
    }
}

// ---- Fallback: R4 direct kernel (used when ws is too small) ----
#define PTS 4
__global__ __launch_bounds__(256) void stroke_direct(
    const float* __restrict__ coords, const float* __restrict__ shape,
    const float* __restrict__ color, const float* __restrict__ alpha,
    float* __restrict__ out, int n, int ns)
{
    __shared__ float4 fA[MAXS + 1];
    __shared__ float4 fB[MAXS + 1];
    for (int s = threadIdx.x; s < ns; s += blockDim.x) {
        float4 sp = ((const float4*)shape)[s];
        fA[s + 1] = make_float4(sp.x, sp.y, sp.z, fmaf(-5.0f, sp.w, 0.5f));
        fB[s + 1] = make_float4(fmaxf(alpha[s], 0.0f) * 50.0f,
                                color[3 * s], color[3 * s + 1], color[3 * s + 2]);
    }
    __syncthreads();
    const int base = blockIdx.x * (blockDim.x * PTS) + threadIdx.x;
    float cx[PTS], cy[PTS], cz[PTS], T[PTS], Ad[PTS], Ar[PTS], Ag[PTS], Ab[PTS];
#pragma unroll
    for (int k = 0; k < PTS; ++k) {
        int i = base + k * 256; i = (i < n) ? i : (n - 1);
        float x = coords[3 * i], y = coords[3 * i + 1], z = coords[3 * i + 2];
        float n2 = fmaf(x, x, fmaf(y, y, z * z));
        float nn = fmaxf(__builtin_amdgcn_sqrtf(n2), 1e-9f);
        float invn = 1.0f / nn;
        float scl = (nn <= 1.0f) ? 0.5f : (2.0f - invn) * (0.5f * invn);
        cx[k] = x * scl; cy[k] = y * scl; cz[k] = z * scl;
        T[k] = 1.0f; Ad[k] = Ar[k] = Ag[k] = Ab[k] = 0.0f;
    }
    float4 a = fA[ns], b = fB[ns];
#pragma unroll 2
    for (int s = ns - 1; s >= 0; --s) {
        float4 an = fA[s], bn = fB[s];
#pragma unroll
        for (int k = 0; k < PTS; ++k) {
            float dx = cx[k] - a.x, dy = cy[k] - a.y, dz = cz[k] - a.z;
            float d2 = fmaf(dx, dx, fmaf(dy, dy, dz * dz));
            float dist = __builtin_amdgcn_sqrtf(d2);
            float omt = fminf(fmaxf(fmaf(5.0f, dist, a.w), 0.0f), 1.0f);
            float Tn = omt * T[k];
            float tT = T[k] - Tn;
            Ad[k] = fmaf(tT, b.x, Ad[k]); Ar[k] = fmaf(tT, b.y, Ar[k]);
            Ag[k] = fmaf(tT, b.z, Ag[k]); Ab[k] = fmaf(tT, b.w, Ab[k]);
            T[k] = Tn;
        }
        a = an; b = bn;
    }
    float* rgb = out + n;
    float* cw  = out + 4 * (size_t)n;
#pragma unroll
    for (int k = 0; k < PTS; ++k) {
        int i = base + k * 256;
        if (i >= n) break;
        float inv = 1.0f / (1.0f + 1e-6f - T[k]);
        out[i] = Ad[k];
        rgb[3 * i]     = fminf(fmaxf(Ar[k] * inv, 0.0f), 1.0f);
        rgb[3 * i + 1] = fminf(fmaxf(Ag[k] * inv, 0.0f), 1.0f);
        rgb[3 * i + 2] = fminf(fmaxf(Ab[k] * inv, 0.0f), 1.0f);
        cw[3 * i]     = cx[k];
        cw[3 * i + 1] = cy[k];
        cw[3 * i + 2] = cz[k];
    }
}

extern "C" void kernel_launch(void* const* d_in, const int* in_sizes, int n_in,
                              void* d_out, int out_size, void* d_ws, size_t ws_size,
                              hipStream_t stream) {
    const float* coords = (const float*)d_in[0];
    const float* shape  = (const float*)d_in[1];
    const float* color  = (const float*)d_in[2];
    const float* alpha  = (const float*)d_in[3];
    float* out = (float*)d_out;

    int n  = in_sizes[0] / 3;
    int ns = in_sizes[1] / 4;

    auto al = [](size_t v) { return (v + 255) & ~(size_t)255; };
    int maxChunks = (n + 63) / 64 + NC + 4;
    size_t o_cnt     = 0;
    size_t o_cursor  = 16384;
    size_t o_cellCnt = 32768;
    size_t o_chunk   = 49152;
    size_t o_cid     = al(o_chunk + (size_t)maxChunks * 8);
    size_t o_list    = al(o_cid + (size_t)n * 4);
    size_t o_sorted  = al(o_list + (size_t)NC * MAXS * 2);
    size_t nslots    = ((size_t)(n + 63) / 64) * 64 + 64 * (size_t)NC;
    size_t need      = o_sorted + nslots * 16;

    if (ws_size >= need && ns <= MAXS && n >= 64) {
        char* w = (char*)d_ws;
        int*    cnt       = (int*)(w + o_cnt);
        int*    cursor    = (int*)(w + o_cursor);
        int*    cellCnt   = (int*)(w + o_cellCnt);
        int2*   chunkInfo = (int2*)(w + o_chunk);
        int*    cid       = (int*)(w + o_cid);
        u16*    cellList  = (u16*)(w + o_list);
        float4* sorted    = (float4*)(w + o_sorted);

        hipMemsetAsync(cnt, 0, NC * 4, stream);
        hipMemsetAsync(chunkInfo, 0xFF, (size_t)maxChunks * 8, stream);
        hipMemsetAsync(sorted, 0xFF, nslots * 16, stream);

        k1_points<<<(n + 255) / 256, 256, 0, stream>>>(coords, out, cid, cnt, n);
        k2_scan<<<1, 1024, 0, stream>>>(cnt, cursor, chunkInfo);
        k3_scatter<<<(n + 255) / 256, 256, 0, stream>>>(out, cid, cursor, sorted, n);
        k4_bin<<<(NC * 64 + 255) / 256, 256, 0, stream>>>(shape, cellList, cellCnt, ns);
        int realChunks = (n + 63) / 64 + NC;
        k5_blend<<<(realChunks + 3) / 4, 256, 0, stream>>>(
            shape, color, alpha, chunkInfo, sorted, cellList, cellCnt, out, n, ns);
    } else {
        int per_block = 256 * PTS;
        int grid = (n + per_block - 1) / per_block;
        stroke_direct<<<grid, 256, 0, stream>>>(coords, shape, color, alpha, out, n, ns);
    }
}

// Round 6
// 310.897 us; speedup vs baseline: 2.0910x; 2.0910x over previous
//
#include <hip/hip_runtime.h>

// StrokeField R6: exact stroke culling + XCD-friendly two-level counting sort.
// R5 post-mortem: device-wide 16B scatter = 121MB amplified HBM writes
// (partial lines from 8 non-coherent XCD L2s), 236us. Fix: two-level sort --
// scatter into 64 supercell regions with block-aggregated runs (KC), then one
// block PER supercell locally sorts into 64-aligned per-cell chunks (KD), so
// all fine-grained writes come from one CU and merge in its L2.
// Blend kernel (KF) = R5's verified k5 (wave-uniform broadcast strokes),
// gathering point coords via 4B sorted indices.

#define NC_DIM 16
#define NC (NC_DIM * NC_DIM * NC_DIM)   // 4096 cells = 64 supercells x 64 sub
#define MAXS 512
#define CELL_INV 8.0f

typedef unsigned short u16;
typedef unsigned long long u64;

__device__ __forceinline__ void contract_pt(float x, float y, float z,
                                            float& cx, float& cy, float& cz) {
    float n2 = fmaf(x, x, fmaf(y, y, z * z));
    float nn = fmaxf(__builtin_amdgcn_sqrtf(n2), 1e-9f);
    float invn = 1.0f / nn;
    float scl = (nn <= 1.0f) ? 0.5f : (2.0f - invn) * (0.5f * invn);
    cx = x * scl; cy = y * scl; cz = z * scl;
}

__device__ __forceinline__ int cid_of(float cx, float cy, float cz) {
    int ix = (int)floorf((cx + 1.0f) * CELL_INV);
    int iy = (int)floorf((cy + 1.0f) * CELL_INV);
    int iz = (int)floorf((cz + 1.0f) * CELL_INV);
    ix = min(max(ix, 0), 15); iy = min(max(iy, 0), 15); iz = min(max(iz, 0), 15);
    return ix | (iy << 4) | (iz << 8);
}
__device__ __forceinline__ int sid_of(int cid) {   // supercell 0..63
    return ((cid >> 2) & 3) | (((cid >> 6) & 3) << 2) | (((cid >> 10) & 3) << 4);
}
__device__ __forceinline__ int sub_of(int cid) {   // subcell 0..63
    return (cid & 3) | (((cid >> 4) & 3) << 2) | (((cid >> 8) & 3) << 4);
}
__device__ __forceinline__ int cid_from(int s, int t) {
    int ix = (((s) & 3) << 2) | (t & 3);
    int iy = (((s >> 2) & 3) << 2) | ((t >> 2) & 3);
    int iz = (((s >> 4) & 3) << 2) | ((t >> 4) & 3);
    return ix | (iy << 4) | (iz << 8);
}

// KA: contract, write cw to out, supercell histogram (LDS-aggregated).
__global__ __launch_bounds__(256) void kA(
    const float* __restrict__ coords, float* __restrict__ out,
    int* __restrict__ superCnt, int n)
{
    __shared__ int h[64];
    if (threadIdx.x < 64) h[threadIdx.x] = 0;
    __syncthreads();
    float* cw = out + 4 * (size_t)n;
    int base = blockIdx.x * 1024 + threadIdx.x;
#pragma unroll
    for (int k = 0; k < 4; ++k) {
        int i = base + k * 256;
        if (i < n) {
            float cx, cy, cz;
            contract_pt(coords[3 * i], coords[3 * i + 1], coords[3 * i + 2], cx, cy, cz);
            cw[3 * i] = cx; cw[3 * i + 1] = cy; cw[3 * i + 2] = cz;
            atomicAdd(&h[sid_of(cid_of(cx, cy, cz))], 1);
        }
    }
    __syncthreads();
    if (threadIdx.x < 64 && h[threadIdx.x])
        atomicAdd(&superCnt[threadIdx.x], h[threadIdx.x]);
}

// KB: 64-wide scan -> per-supercell chunk base + slot cursor (padded).
__global__ __launch_bounds__(64) void kB(
    const int* __restrict__ superCnt, int* __restrict__ superChunkBase,
    int* __restrict__ superCursor)
{
    int t = threadIdx.x;
    int cnt = superCnt[t];
    int cap = ((cnt + 63) >> 6) + 65;       // chunks: cells' ceil-pad bound
    int v = cap;
    for (int off = 1; off < 64; off <<= 1) {
        int u = __shfl_up(v, off, 64);
        if (t >= off) v += u;
    }
    int excl = v - cap;
    superChunkBase[t] = excl;
    superCursor[t] = excl << 6;             // slot cursor for KC
}

// KC: block-aggregated scatter of (idx,cid) into 64 supercell regions.
__global__ __launch_bounds__(256) void kC(
    const float* __restrict__ out, int* __restrict__ superCursor,
    int2* __restrict__ idxTmp, int n)
{
    __shared__ int scnt[64], sbase[64];
    if (threadIdx.x < 64) scnt[threadIdx.x] = 0;
    __syncthreads();
    const float* cw = out + 4 * (size_t)n;
    int base = blockIdx.x * 2048 + threadIdx.x;
    int sid[8], cid[8];
#pragma unroll
    for (int k = 0; k < 8; ++k) {
        int i = base + k * 256;
        if (i < n) {
            int c = cid_of(cw[3 * i], cw[3 * i + 1], cw[3 * i + 2]);
            cid[k] = c; sid[k] = sid_of(c);
            atomicAdd(&scnt[sid[k]], 1);
        } else sid[k] = -1;
    }
    __syncthreads();
    if (threadIdx.x < 64) {
        int c = scnt[threadIdx.x];
        sbase[threadIdx.x] = c ? atomicAdd(&superCursor[threadIdx.x], c) : 0;
        scnt[threadIdx.x] = 0;
    }
    __syncthreads();
#pragma unroll
    for (int k = 0; k < 8; ++k) {
        if (sid[k] >= 0) {
            int i = base + k * 256;
            int r = atomicAdd(&scnt[sid[k]], 1);
            idxTmp[sbase[sid[k]] + r] = make_int2(i, cid[k]);
        }
    }
}

// KD: one block per supercell; local counting sort into 64-aligned cell runs.
__global__ __launch_bounds__(1024) void kD(
    const int* __restrict__ superCnt, const int* __restrict__ superChunkBase,
    const int2* __restrict__ idxTmp, int* __restrict__ idxFinal,
    int2* __restrict__ chunkInfo, int* __restrict__ cellCnt)
{
    __shared__ int cnt64[64], cur[64];
    int s = blockIdx.x, t = threadIdx.x;
    if (t < 64) cnt64[t] = 0;
    __syncthreads();
    int cntS = superCnt[s];
    int cb = superChunkBase[s];
    int slotBase = cb << 6;
    for (int j = t; j < cntS; j += 1024)
        atomicAdd(&cnt64[sub_of(idxTmp[slotBase + j].y)], 1);
    __syncthreads();
    if (t < 64) {
        int c = cnt64[t];
        int ch = (c + 63) >> 6;
        int v = ch;
        for (int off = 1; off < 64; off <<= 1) {
            int u = __shfl_up(v, off, 64);
            if (t >= off) v += u;
        }
        int chOff = v - ch;
        int st = chOff << 6;
        cur[t] = st;
        int cid = cid_from(s, t);
        cellCnt[cid] = c;
        for (int q = 0; q < ch; ++q)
            chunkInfo[cb + chOff + q] = make_int2(cid, slotBase + st + (q << 6));
    }
    __syncthreads();
    for (int j = t; j < cntS; j += 1024) {
        int2 r = idxTmp[slotBase + j];
        int pos = atomicAdd(&cur[sub_of(r.y)], 1);
        idxFinal[slotBase + pos] = r.x;
    }
}

// KE: per-cell ordered stroke sublist (AABB vs sphere, exact-zero margin).
__global__ __launch_bounds__(256) void kE(
    const float* __restrict__ shape, u16* __restrict__ cellList,
    int ns)
{
    int wave = (blockIdx.x * blockDim.x + threadIdx.x) >> 6;
    int lane = threadIdx.x & 63;
    if (wave >= NC) return;
    int ix = wave & 15, iy = (wave >> 4) & 15, iz = wave >> 8;
    float lox = -1.0f + ix * 0.125f, hix = lox + 0.125f;
    float loy = -1.0f + iy * 0.125f, hiy = loy + 0.125f;
    float loz = -1.0f + iz * 0.125f, hiz = loz + 0.125f;
    int cnt = 0;
    u16* lst = cellList + (size_t)wave * MAXS;
    for (int base = 0; base < ns; base += 64) {
        int s = base + lane;
        bool pass = false;
        if (s < ns) {
            float4 sp = ((const float4*)shape)[s];
            float dx = sp.x - fminf(fmaxf(sp.x, lox), hix);
            float dy = sp.y - fminf(fmaxf(sp.y, loy), hiy);
            float dz = sp.z - fminf(fmaxf(sp.z, loz), hiz);
            float d2 = fmaf(dx, dx, fmaf(dy, dy, dz * dz));
            float rr = sp.w + 0.101f;
            pass = d2 <= rr * rr;
        }
        u64 m = __ballot(pass);
        if (pass) lst[cnt + __popcll(m & ((1ull << lane) - 1ull))] = (u16)s;
        cnt += __popcll(m);
    }
    // count is re-derived by KD? no: stroke list count per cell:
    // store in high slot? cellCnt is per-POINT count. Use separate array:
    // (written via pointer aliasing below)
    if (lane == 0) ((int*)(cellList + (size_t)NC * MAXS))[wave] = cnt;
}

// KF: one wave per chunk; blend the cell's stroke sublist (R5-verified math).
__global__ __launch_bounds__(256) void kF(
    const float* __restrict__ shape, const float* __restrict__ color,
    const float* __restrict__ alpha,
    const int2* __restrict__ chunkInfo, const int* __restrict__ idxFinal,
    const u16* __restrict__ cellList, const int* __restrict__ strokeCnt,
    float* __restrict__ out, int n, int ns, int maxChunks)
{
    __shared__ float4 sA[MAXS];   // (ax, ay, az, K = 0.5 - 5r)
    __shared__ float4 sB[MAXS];   // (dp, cr, cg, cb)
    for (int s = threadIdx.x; s < ns; s += blockDim.x) {
        float4 sp = ((const float4*)shape)[s];
        sA[s] = make_float4(sp.x, sp.y, sp.z, fmaf(-5.0f, sp.w, 0.5f));
        sB[s] = make_float4(fmaxf(alpha[s], 0.0f) * 50.0f,
                            color[3 * s], color[3 * s + 1], color[3 * s + 2]);
    }
    __syncthreads();

    int k = blockIdx.x * 4 + (threadIdx.x >> 6);
    int lane = threadIdx.x & 63;
    if (k >= maxChunks) return;
    int2 info = chunkInfo[k];
    int cell = info.x;
    if (cell < 0) return;

    int idx = idxFinal[info.y + lane];
    bool valid = idx >= 0;
    const float* cw = out + 4 * (size_t)n;
    float cx = 1e9f, cy = 1e9f, cz = 1e9f;
    if (valid) { cx = cw[3 * idx]; cy = cw[3 * idx + 1]; cz = cw[3 * idx + 2]; }

    int nl = strokeCnt[cell];
    const u16* lst = cellList + (size_t)cell * MAXS;

    float T = 1.0f, Ad = 0.0f, Ar = 0.0f, Ag = 0.0f, Ab = 0.0f;
    for (int jb = (((nl + 63) >> 6) << 6) - 64; jb >= 0; jb -= 64) {
        int jl = jb + lane;
        int myId = (jl < nl) ? (int)lst[jl] : 0;
        int hi = nl - jb; hi = hi > 64 ? 64 : hi;
        int sid = __builtin_amdgcn_readlane(myId, hi - 1);
        float4 a = sA[sid];
        float4 b = sB[sid];
        for (int jj = hi - 1; jj >= 0; --jj) {
            int sidn = __builtin_amdgcn_readlane(myId, jj > 0 ? jj - 1 : 0);
            float4 an = sA[sidn];
            float4 bn = sB[sidn];
            float dx = cx - a.x, dy = cy - a.y, dz = cz - a.z;
            float d2 = fmaf(dx, dx, fmaf(dy, dy, dz * dz));
            float dist = __builtin_amdgcn_sqrtf(d2);
            float omt = fminf(fmaxf(fmaf(5.0f, dist, a.w), 0.0f), 1.0f);
            float Tn = omt * T;
            float tT = T - Tn;
            Ad = fmaf(tT, b.x, Ad);
            Ar = fmaf(tT, b.y, Ar);
            Ag = fmaf(tT, b.z, Ag);
            Ab = fmaf(tT, b.w, Ab);
            T = Tn;
            a = an; b = bn;
        }
    }

    if (valid) {
        float inv = 1.0f / (1.0f + 1e-6f - T);
        out[idx] = Ad;
        float* rgb = out + n;
        rgb[3 * idx]     = fminf(fmaxf(Ar * inv, 0.0f), 1.0f);
        rgb[3 * idx + 1] = fminf(fmaxf(Ag * inv, 0.0f), 1.0f);
        rgb[3 * idx + 2] = fminf(fmaxf(Ab * inv, 0.0f), 1.0f);
    }
}

// ---- Fallback: R4 direct kernel ----
#define PTS 4
__global__ __launch_bounds__(256) void stroke_direct(
    const float* __restrict__ coords, const float* __restrict__ shape,
    const float* __restrict__ color, const float* __restrict__ alpha,
    float* __restrict__ out, int n, int ns)
{
    __shared__ float4 fA[MAXS + 1];
    __shared__ float4 fB[MAXS + 1];
    for (int s = threadIdx.x; s < ns; s += blockDim.x) {
        float4 sp = ((const float4*)shape)[s];
        fA[s + 1] = make_float4(sp.x, sp.y, sp.z, fmaf(-5.0f, sp.w, 0.5f));
        fB[s + 1] = make_float4(fmaxf(alpha[s], 0.0f) * 50.0f,
                                color[3 * s], color[3 * s + 1], color[3 * s + 2]);
    }
    __syncthreads();
    const int base = blockIdx.x * (blockDim.x * PTS) + threadIdx.x;
    float cx[PTS], cy[PTS], cz[PTS], T[PTS], Ad[PTS], Ar[PTS], Ag[PTS], Ab[PTS];
#pragma unroll
    for (int k = 0; k < PTS; ++k) {
        int i = base + k * 256; i = (i < n) ? i : (n - 1);
        contract_pt(coords[3 * i], coords[3 * i + 1], coords[3 * i + 2],
                    cx[k], cy[k], cz[k]);
        T[k] = 1.0f; Ad[k] = Ar[k] = Ag[k] = Ab[k] = 0.0f;
    }
    float4 a = fA[ns], b = fB[ns];
#pragma unroll 2
    for (int s = ns - 1; s >= 0; --s) {
        float4 an = fA[s], bn = fB[s];
#pragma unroll
        for (int k = 0; k < PTS; ++k) {
            float dx = cx[k] - a.x, dy = cy[k] - a.y, dz = cz[k] - a.z;
            float d2 = fmaf(dx, dx, fmaf(dy, dy, dz * dz));
            float dist = __builtin_amdgcn_sqrtf(d2);
            float omt = fminf(fmaxf(fmaf(5.0f, dist, a.w), 0.0f), 1.0f);
            float Tn = omt * T[k];
            float tT = T[k] - Tn;
            Ad[k] = fmaf(tT, b.x, Ad[k]); Ar[k] = fmaf(tT, b.y, Ar[k]);
            Ag[k] = fmaf(tT, b.z, Ag[k]); Ab[k] = fmaf(tT, b.w, Ab[k]);
            T[k] = Tn;
        }
        a = an; b = bn;
    }
    float* rgb = out + n;
    float* cw  = out + 4 * (size_t)n;
#pragma unroll
    for (int k = 0; k < PTS; ++k) {
        int i = base + k * 256;
        if (i >= n) break;
        float inv = 1.0f / (1.0f + 1e-6f - T[k]);
        out[i] = Ad[k];
        rgb[3 * i]     = fminf(fmaxf(Ar[k] * inv, 0.0f), 1.0f);
        rgb[3 * i + 1] = fminf(fmaxf(Ag[k] * inv, 0.0f), 1.0f);
        rgb[3 * i + 2] = fminf(fmaxf(Ab[k] * inv, 0.0f), 1.0f);
        cw[3 * i]     = cx[k];
        cw[3 * i + 1] = cy[k];
        cw[3 * i + 2] = cz[k];
    }
}

extern "C" void kernel_launch(void* const* d_in, const int* in_sizes, int n_in,
                              void* d_out, int out_size, void* d_ws, size_t ws_size,
                              hipStream_t stream) {
    const float* coords = (const float*)d_in[0];
    const float* shape  = (const float*)d_in[1];
    const float* color  = (const float*)d_in[2];
    const float* alpha  = (const float*)d_in[3];
    float* out = (float*)d_out;

    int n  = in_sizes[0] / 3;
    int ns = in_sizes[1] / 4;

    auto al = [](size_t v) { return (v + 255) & ~(size_t)255; };
    int maxChunks = (n + 63) / 64 + 4224;
    size_t nslots = (size_t)maxChunks * 64;
    size_t o_superCnt = 0;
    size_t o_superCB  = 256;
    size_t o_superCur = 512;
    size_t o_cellCnt  = 768;                                  // point counts (unused now)
    size_t o_chunk    = al(o_cellCnt + NC * 4);
    size_t o_list     = al(o_chunk + (size_t)maxChunks * 8);  // u16 lists + int counts
    size_t o_tmp      = al(o_list + (size_t)NC * MAXS * 2 + NC * 4);
    size_t o_final    = al(o_tmp + nslots * 8);
    size_t need       = o_final + nslots * 4;

    if (ws_size >= need && ns <= MAXS && n >= 1) {
        char* w = (char*)d_ws;
        int*  superCnt = (int*)(w + o_superCnt);
        int*  superCB  = (int*)(w + o_superCB);
        int*  superCur = (int*)(w + o_superCur);
        int2* chunkInfo = (int2*)(w + o_chunk);
        u16*  cellList = (u16*)(w + o_list);
        int*  strokeCnt = (int*)(w + o_list + (size_t)NC * MAXS * 2);
        int2* idxTmp   = (int2*)(w + o_tmp);
        int*  idxFinal = (int*)(w + o_final);

        hipMemsetAsync(superCnt, 0, 256, stream);
        hipMemsetAsync(chunkInfo, 0xFF, (size_t)maxChunks * 8, stream);
        hipMemsetAsync(idxFinal, 0xFF, nslots * 4, stream);

        kA<<<(n + 1023) / 1024, 256, 0, stream>>>(coords, out, superCnt, n);
        kB<<<1, 64, 0, stream>>>(superCnt, superCB, superCur);
        kC<<<(n + 2047) / 2048, 256, 0, stream>>>(out, superCur, idxTmp, n);
        kD<<<64, 1024, 0, stream>>>(superCnt, superCB, idxTmp, idxFinal,
                                    chunkInfo, (int*)(w + o_cellCnt));
        kE<<<(NC * 64 + 255) / 256, 256, 0, stream>>>(shape, cellList, ns);
        kF<<<(maxChunks + 3) / 4, 256, 0, stream>>>(
            shape, color, alpha, chunkInfo, idxFinal, cellList, strokeCnt,
            out, n, ns, maxChunks);
    } else {
        int per_block = 256 * PTS;
        int grid = (n + per_block - 1) / per_block;
        stroke_direct<<<grid, 256, 0, stream>>>(coords, shape, color, alpha, out, n, ns);
    }
}